// Round 4
// baseline (351.018 us; speedup 1.0000x reference)
//
#include <hip/hip_runtime.h>
#include <hip/hip_bf16.h>
#include <math.h>

#define IMG 128
#define PATCH 16
#define L 64
#define D 256
#define DIN 512
#define DH 64
#define H 8
#define NSTATE 64
#define DCONV 4
#define DEPTH 2
#define NCLS 1000
#define BATCH 16
#define DINPROJ 1160   // 2*DIN + 2*N + H
#define CDIM 640       // DIN + 2*N
#define EPS 1e-6f

typedef __attribute__((ext_vector_type(8))) short short8;
typedef __attribute__((ext_vector_type(4))) float f32x4;
typedef __attribute__((ext_vector_type(4))) unsigned short us4;
typedef unsigned short ushort_t;

__device__ __forceinline__ int snake_tok(int s){
    int r = s >> 3, c = s & 7;
    return (r & 1) ? (r * 8 + (7 - c)) : (r * 8 + c);
}
__device__ __forceinline__ float silu_f(float x){ return x / (1.f + expf(-x)); }
__device__ __forceinline__ float softplus_f(float x){ return x > 20.f ? x : log1pf(expf(x)); }
__device__ __forceinline__ ushort_t f2b(float f){
    __hip_bfloat16 h = __float2bfloat16(f);
    return *(ushort_t*)&h;
}

// ---------------- weight convert: Win/Wout transposed to [N][K] bf16; patch_w copied
__global__ void wconv_k(const float* __restrict__ Win0, const float* __restrict__ Win1,
                        const float* __restrict__ Wout0, const float* __restrict__ Wout1,
                        const float* __restrict__ pw, ushort_t* __restrict__ wbuf){
    int z = blockIdx.z;
    if (z == 8){
        int id = (blockIdx.y * 37 + blockIdx.x) * 256 + threadIdx.x;
        for (; id < 196608; id += 37 * 16 * 256)
            wbuf[id] = f2b(pw[id]);
        return;
    }
    __shared__ float sm[32][33];
    int R, C; const float* src; ushort_t* dst;
    if (z < 4){
        int layer = z >> 1, dir = z & 1;
        src = (dir ? Win1 : Win0) + (size_t)layer * D * DINPROJ;
        dst = wbuf + 196608 + (size_t)z * 296960;
        R = D; C = DINPROJ;
    } else {
        int zz = z - 4, layer = zz >> 1, dir = zz & 1;
        src = (dir ? Wout1 : Wout0) + (size_t)layer * DIN * D;
        dst = wbuf + 1384448 + (size_t)zz * 131072;
        R = DIN; C = D;
    }
    int ctiles = (C + 31) >> 5, rtiles = R >> 5;
    if (blockIdx.x >= ctiles || blockIdx.y >= rtiles) return;
    int c0 = blockIdx.x * 32, r0 = blockIdx.y * 32;
    int tx = threadIdx.x & 31, ty = threadIdx.x >> 5;
    #pragma unroll
    for (int k = 0; k < 4; ++k){
        int r = r0 + ty + 8 * k, c = c0 + tx;
        sm[ty + 8 * k][tx] = (c < C) ? src[(size_t)r * C + c] : 0.f;
    }
    __syncthreads();
    #pragma unroll
    for (int k = 0; k < 4; ++k){
        int dr = c0 + ty + 8 * k, dc = r0 + tx;
        if (dr < C) dst[(size_t)dr * R + dc] = f2b(sm[tx][ty + 8 * k]);
    }
}

// ---------------- patch GEMM with fused patchify gather + bias/pos epilogue
// C[b*64+s][n] = sum_k patch(b,s,k) * pw_bf[n][k] + pb[n] + pos[snake(s)][n]
__global__ __launch_bounds__(256) void gemm_patch_k(
    const float* __restrict__ x, const ushort_t* __restrict__ Bw,
    float* __restrict__ C, const float* __restrict__ pb, const float* __restrict__ pos)
{
    __shared__ __align__(16) ushort_t As[2][64][40];
    __shared__ __align__(16) ushort_t Bs[2][64][40];
    const int t = threadIdx.x;
    const int n0 = blockIdx.x * 64;
    const int b  = blockIdx.y;              // m0 = b*64
    const int lrow = t >> 2, lc8 = (t & 3) * 8;
    const int tok = snake_tok(lrow), gy = tok >> 3, gx = tok & 7;
    const float* xb = x + (size_t)b * 3 * IMG * IMG;
    const int wave = t >> 6, lane = t & 63;
    const int wm = (wave >> 1) * 32, wn = (wave & 1) * 32;
    const int fro = lane & 15, fk = (lane >> 4) * 8;

    f32x4 acc[2][2];
    #pragma unroll
    for (int i = 0; i < 2; ++i)
        #pragma unroll
        for (int j = 0; j < 2; ++j) acc[i][j] = (f32x4){0.f,0.f,0.f,0.f};

    short8 areg; float4 breg;
    auto gload = [&](int kk){
        int k = kk + lc8;
        int c = k >> 8, rem = k & 255, py = rem >> 4, px = rem & 15;
        const float* src = xb + ((size_t)c * IMG + gy * PATCH + py) * IMG + gx * PATCH + px;
        float4 a0 = *(const float4*)(src);
        float4 a1 = *(const float4*)(src + 4);
        ushort_t tmp[8] = {f2b(a0.x),f2b(a0.y),f2b(a0.z),f2b(a0.w),
                           f2b(a1.x),f2b(a1.y),f2b(a1.z),f2b(a1.w)};
        areg = *(short8*)tmp;
        breg = *(const float4*)(Bw + (size_t)(n0 + lrow) * 768 + kk + lc8);
    };
    auto sstore = [&](int buf){
        *(short8*)&As[buf][lrow][lc8] = areg;
        *(float4*)&Bs[buf][lrow][lc8] = breg;
    };

    const int nk = 768 / 32;
    gload(0); sstore(0);
    __syncthreads();
    for (int kt = 0; kt < nk; ++kt){
        const int buf = kt & 1;
        if (kt + 1 < nk) gload((kt + 1) * 32);
        short8 af[2], bfr[2];
        af[0]  = *(const short8*)&As[buf][wm + fro][fk];
        af[1]  = *(const short8*)&As[buf][wm + 16 + fro][fk];
        bfr[0] = *(const short8*)&Bs[buf][wn + fro][fk];
        bfr[1] = *(const short8*)&Bs[buf][wn + 16 + fro][fk];
        #pragma unroll
        for (int i = 0; i < 2; ++i)
            #pragma unroll
            for (int j = 0; j < 2; ++j)
                acc[i][j] = __builtin_amdgcn_mfma_f32_16x16x32_bf16(af[i], bfr[j], acc[i][j], 0, 0, 0);
        if (kt + 1 < nk) sstore(buf ^ 1);
        __syncthreads();
    }
    #pragma unroll
    for (int i = 0; i < 2; ++i){
        #pragma unroll
        for (int j = 0; j < 2; ++j){
            int col = n0 + wn + j * 16 + (lane & 15);
            #pragma unroll
            for (int r = 0; r < 4; ++r){
                int srow = wm + i * 16 + (lane >> 4) * 4 + r;   // token s
                C[(size_t)(b * 64 + srow) * D + col] =
                    acc[i][j][r] + pb[col] + pos[snake_tok(srow) * D + col];
            }
        }
    }
}

// ---------------- in-proj GEMM with fused rmsnorm prologue.
// A = rmsnorm(t[m],nw) in bf16 (computed in-block), B = Win_bf [1160][256]. C=zx f32.
__global__ __launch_bounds__(256) void gemm_in_k(
    const float* __restrict__ T, const float* __restrict__ nw,
    const ushort_t* __restrict__ B0, const ushort_t* __restrict__ B1,
    float* __restrict__ C0, float* __restrict__ C1)
{
    __shared__ __align__(16) ushort_t As[64][264];      // 33792 B, stride 528B (16B mult)
    __shared__ __align__(16) ushort_t Bs[2][64][40];    // 10240 B
    const int dir = blockIdx.z;
    const ushort_t* __restrict__ Bw = dir ? B1 : B0;
    float* __restrict__ C = dir ? C1 : C0;
    const int t = threadIdx.x;
    const int m0 = blockIdx.y * 64, n0 = blockIdx.x * 64;
    const int arow = t >> 2;
    const int wave = t >> 6, lane = t & 63;
    const int wm = (wave >> 1) * 32, wn = (wave & 1) * 32;
    const int fro = lane & 15, fk = (lane >> 4) * 8;

    // --- prologue: rmsnorm rows m0..m0+63 into As (bf16) ---
    {
        const float* src = T + (size_t)(m0 + arow) * D;
        float ss = 0.f;
        #pragma unroll
        for (int i = 0; i < 16; ++i){
            int c = (t & 3) * 4 + i * 16;
            float4 v = *(const float4*)(src + c);
            ss += v.x*v.x + v.y*v.y + v.z*v.z + v.w*v.w;
        }
        ss += __shfl_xor(ss, 1);
        ss += __shfl_xor(ss, 2);
        float sc = rsqrtf(ss * (1.f / (float)D) + EPS);
        #pragma unroll
        for (int i = 0; i < 16; ++i){
            int c = (t & 3) * 4 + i * 16;
            float4 v = *(const float4*)(src + c);
            float4 w = *(const float4*)(nw + c);
            us4 o = {f2b(v.x*sc*w.x), f2b(v.y*sc*w.y), f2b(v.z*sc*w.z), f2b(v.w*sc*w.w)};
            *(us4*)&As[arow][c] = o;
        }
    }
    // --- B staging ---
    const int lrow = t >> 2, lc8 = (t & 3) * 8;
    float4 breg;
    auto gloadB = [&](int kk){
        int gn = n0 + lrow;
        if (gn < DINPROJ) breg = *(const float4*)(Bw + (size_t)gn * D + kk + lc8);
        else breg = make_float4(0.f,0.f,0.f,0.f);
    };
    auto sstoreB = [&](int buf){ *(float4*)&Bs[buf][lrow][lc8] = breg; };

    f32x4 acc[2][2];
    #pragma unroll
    for (int i = 0; i < 2; ++i)
        #pragma unroll
        for (int j = 0; j < 2; ++j) acc[i][j] = (f32x4){0.f,0.f,0.f,0.f};

    gloadB(0); sstoreB(0);
    __syncthreads();
    const int nk = D / 32;
    for (int kt = 0; kt < nk; ++kt){
        const int buf = kt & 1;
        if (kt + 1 < nk) gloadB((kt + 1) * 32);
        short8 af[2], bfr[2];
        af[0]  = *(const short8*)&As[wm + fro][kt * 32 + fk];
        af[1]  = *(const short8*)&As[wm + 16 + fro][kt * 32 + fk];
        bfr[0] = *(const short8*)&Bs[buf][wn + fro][fk];
        bfr[1] = *(const short8*)&Bs[buf][wn + 16 + fro][fk];
        #pragma unroll
        for (int i = 0; i < 2; ++i)
            #pragma unroll
            for (int j = 0; j < 2; ++j)
                acc[i][j] = __builtin_amdgcn_mfma_f32_16x16x32_bf16(af[i], bfr[j], acc[i][j], 0, 0, 0);
        if (kt + 1 < nk) sstoreB(buf ^ 1);
        __syncthreads();
    }
    #pragma unroll
    for (int i = 0; i < 2; ++i){
        #pragma unroll
        for (int j = 0; j < 2; ++j){
            int col = n0 + wn + j * 16 + (lane & 15);
            if (col >= DINPROJ) continue;
            #pragma unroll
            for (int r = 0; r < 4; ++r){
                int row = m0 + wm + i * 16 + (lane >> 4) * 4 + r;
                C[(size_t)row * DINPROJ + col] = acc[i][j][r];
            }
        }
    }
}

// ---------------- out-proj GEMM: both dirs accumulated, epilogue t += 0.5*acc
__global__ __launch_bounds__(256) void gemm_out_k(
    const ushort_t* __restrict__ A0, const ushort_t* __restrict__ A1,
    const ushort_t* __restrict__ B0, const ushort_t* __restrict__ B1,
    float* __restrict__ T)
{
    __shared__ __align__(16) ushort_t As[2][64][40];
    __shared__ __align__(16) ushort_t Bs[2][64][40];
    const int t = threadIdx.x;
    const int n0 = blockIdx.x * 64, m0 = blockIdx.y * 64;
    const int lrow = t >> 2, lc8 = (t & 3) * 8;
    const int wave = t >> 6, lane = t & 63;
    const int wm = (wave >> 1) * 32, wn = (wave & 1) * 32;
    const int fro = lane & 15, fk = (lane >> 4) * 8;

    float4 areg, breg;
    auto gload = [&](int tile){
        int d = tile >> 4, kk = (tile & 15) * 32;
        const ushort_t* A = d ? A1 : A0;
        const ushort_t* B = d ? B1 : B0;
        areg = *(const float4*)(A + (size_t)(m0 + lrow) * DIN + kk + lc8);
        breg = *(const float4*)(B + (size_t)(n0 + lrow) * DIN + kk + lc8);
    };
    auto sstore = [&](int buf){
        *(float4*)&As[buf][lrow][lc8] = areg;
        *(float4*)&Bs[buf][lrow][lc8] = breg;
    };

    f32x4 acc[2][2];
    #pragma unroll
    for (int i = 0; i < 2; ++i)
        #pragma unroll
        for (int j = 0; j < 2; ++j) acc[i][j] = (f32x4){0.f,0.f,0.f,0.f};

    const int nk = 32;   // 16 tiles per dir
    gload(0); sstore(0);
    __syncthreads();
    for (int kt = 0; kt < nk; ++kt){
        const int buf = kt & 1;
        if (kt + 1 < nk) gload(kt + 1);
        short8 af[2], bfr[2];
        af[0]  = *(const short8*)&As[buf][wm + fro][fk];
        af[1]  = *(const short8*)&As[buf][wm + 16 + fro][fk];
        bfr[0] = *(const short8*)&Bs[buf][wn + fro][fk];
        bfr[1] = *(const short8*)&Bs[buf][wn + 16 + fro][fk];
        #pragma unroll
        for (int i = 0; i < 2; ++i)
            #pragma unroll
            for (int j = 0; j < 2; ++j)
                acc[i][j] = __builtin_amdgcn_mfma_f32_16x16x32_bf16(af[i], bfr[j], acc[i][j], 0, 0, 0);
        if (kt + 1 < nk) sstore(buf ^ 1);
        __syncthreads();
    }
    #pragma unroll
    for (int i = 0; i < 2; ++i){
        #pragma unroll
        for (int j = 0; j < 2; ++j){
            int col = n0 + wn + j * 16 + (lane & 15);
            #pragma unroll
            for (int r = 0; r < 4; ++r){
                int row = m0 + wm + i * 16 + (lane >> 4) * 4 + r;
                T[(size_t)row * D + col] += 0.5f * acc[i][j][r];
            }
        }
    }
}

// ---------------- scanprep: dt softplus+prefix, conv+silu, S = C.B^T; grid (2,B)
__global__ __launch_bounds__(512) void scanprep_k(
    const float* __restrict__ zx0, const float* __restrict__ zx1,
    const float* __restrict__ cw0, const float* __restrict__ cw1,
    const float* __restrict__ cb0, const float* __restrict__ cb1,
    const float* __restrict__ dtb0, const float* __restrict__ dtb1,
    const float* __restrict__ Al0, const float* __restrict__ Al1,
    float* __restrict__ xbc0, float* __restrict__ xbc1,
    float* __restrict__ dts0, float* __restrict__ dts1,
    float* __restrict__ cums0, float* __restrict__ cums1,
    float* __restrict__ S0, float* __restrict__ S1)
{
    __shared__ float Bc[64][65];
    __shared__ float Cc[64][65];
    const int dir = blockIdx.x, b = blockIdx.y;
    const float* zx  = dir ? zx1  : zx0;
    const float* cw  = dir ? cw1  : cw0;
    const float* cb  = dir ? cb1  : cb0;
    const float* dtb = dir ? dtb1 : dtb0;
    const float* Al  = dir ? Al1  : Al0;
    float* xbc  = dir ? xbc1  : xbc0;
    float* dts  = dir ? dts1  : dts0;
    float* cums = dir ? cums1 : cums0;
    float* S    = dir ? S1    : S0;
    const int t = threadIdx.x, wave = t >> 6, lane = t & 63;

    // phase 1: dt + prefix scan (wave = h)
    {
        int h = wave, s = lane;
        int l = dir ? (L - 1 - s) : s;
        float xr = zx[(size_t)(b * L + l) * DINPROJ + DIN + CDIM + h] + dtb[h];
        float dt = softplus_f(xr);
        float val = -expf(Al[h]) * dt;
        #pragma unroll
        for (int o = 1; o < 64; o <<= 1){
            float u = __shfl_up(val, o);
            if (lane >= o) val += u;
        }
        dts[(size_t)(b * L + s) * H + h]  = dt;
        cums[(size_t)(b * L + s) * H + h] = val;
    }
    // phase 2: conv + silu
    for (int i = t; i < L * CDIM; i += 512){
        int s = i / CDIM, c = i - s * CDIM;
        float acc = cb[c];
        #pragma unroll
        for (int k = 0; k < DCONV; ++k){
            int j = s - (DCONV - 1) + k;
            if (j >= 0){
                int l = dir ? (L - 1 - j) : j;
                acc += cw[c * DCONV + k] * zx[(size_t)(b * L + l) * DINPROJ + DIN + c];
            }
        }
        float v = silu_f(acc);
        if (c < DIN)            xbc[(size_t)(b * L + s) * DIN + c] = v;
        else if (c < DIN + 64)  Bc[s][c - DIN] = v;
        else                    Cc[s][c - DIN - 64] = v;
    }
    __syncthreads();
    // phase 3: S[s][j] = Cc[s] . Bc[j]
    for (int i = t; i < 64 * 64; i += 512){
        int s = i >> 6, j = i & 63;
        float acc = 0.f;
        #pragma unroll
        for (int n = 0; n < 64; ++n) acc += Cc[s][n] * Bc[j][n];
        S[((size_t)b * L + s) * L + j] = acc;
    }
}

// ---------------- Y; grid (H, B, 2); xbc row stride now DIN
__global__ __launch_bounds__(256) void yscan_k(const float* __restrict__ S0,
                                               const float* __restrict__ S1,
                                               const float* __restrict__ xbc0,
                                               const float* __restrict__ xbc1,
                                               const float* __restrict__ dts0,
                                               const float* __restrict__ dts1,
                                               const float* __restrict__ cums0,
                                               const float* __restrict__ cums1,
                                               const float* __restrict__ Dp0,
                                               const float* __restrict__ Dp1,
                                               float* __restrict__ y0,
                                               float* __restrict__ y1){
    int dir = blockIdx.z;
    const float* S = dir ? S1 : S0;
    const float* xbc = dir ? xbc1 : xbc0;
    const float* dts = dir ? dts1 : dts0;
    const float* cums = dir ? cums1 : cums0;
    const float* Dp = dir ? Dp1 : Dp0;
    float* y = dir ? y1 : y0;
    __shared__ float Am[64][65];
    __shared__ float Xs[64][65];
    __shared__ float cumS[64], dtS[64];
    int h = blockIdx.x, b = blockIdx.y;
    if (threadIdx.x < 64){
        cumS[threadIdx.x] = cums[(size_t)(b * L + threadIdx.x) * H + h];
        dtS[threadIdx.x]  = dts[(size_t)(b * L + threadIdx.x) * H + h];
    }
    for (int idx = threadIdx.x; idx < 64 * 64; idx += 256){
        int j = idx >> 6, pcol = idx & 63;
        Xs[j][pcol] = xbc[(size_t)(b * L + j) * DIN + h * DH + pcol];
        Am[j][pcol] = S[((size_t)b * L + j) * L + pcol];
    }
    __syncthreads();
    for (int idx = threadIdx.x; idx < 64 * 64; idx += 256){
        int s = idx >> 6, j = idx & 63;
        float v = 0.f;
        if (j <= s) v = Am[s][j] * expf(cumS[s] - cumS[j]) * dtS[j];
        Am[s][j] = v;
    }
    __syncthreads();
    float dp = Dp[h];
    for (int idx = threadIdx.x; idx < 64 * 64; idx += 256){
        int s = idx >> 6, pcol = idx & 63;
        float acc = dp * Xs[s][pcol];
        #pragma unroll
        for (int j = 0; j < 64; ++j) acc += Am[s][j] * Xs[j][pcol];
        int l = dir ? (L - 1 - s) : s;
        y[(size_t)(b * L + l) * DIN + h * DH + pcol] = acc;
    }
}

__device__ __forceinline__ float block_sum256(float v){
    __shared__ float sm[4];
    #pragma unroll
    for (int o = 32; o > 0; o >>= 1) v += __shfl_down(v, o);
    if ((threadIdx.x & 63) == 0) sm[threadIdx.x >> 6] = v;
    __syncthreads();
    return sm[0] + sm[1] + sm[2] + sm[3];
}

// ---------------- ybf = bf16(rmsnorm(y * silu(z), gn)); grid (BL, 2)
__global__ void gate_rmsnorm_k(const float* __restrict__ y0, const float* __restrict__ y1,
                               const float* __restrict__ zx0, const float* __restrict__ zx1,
                               const float* __restrict__ gn0, const float* __restrict__ gn1,
                               ushort_t* __restrict__ ybf0, ushort_t* __restrict__ ybf1){
    int dir = blockIdx.y;
    const float* y = dir ? y1 : y0;
    const float* zx = dir ? zx1 : zx0;
    const float* gn = dir ? gn1 : gn0;
    ushort_t* ybf = dir ? ybf1 : ybf0;
    int row = blockIdx.x;
    float g[2]; float ss = 0.f;
    #pragma unroll
    for (int r = 0; r < 2; ++r){
        int c = threadIdx.x + 256 * r;
        float z = zx[(size_t)row * DINPROJ + c];
        float val = y[(size_t)row * DIN + c] * silu_f(z);
        g[r] = val; ss += val * val;
    }
    float tot = block_sum256(ss);
    float sc = rsqrtf(tot / (float)DIN + EPS);
    #pragma unroll
    for (int r = 0; r < 2; ++r){
        int c = threadIdx.x + 256 * r;
        ybf[(size_t)row * DIN + c] = f2b(g[r] * sc * gn[c]);
    }
}

// ---------------- fused final rmsnorm + mean over L; grid (B), 256 thr
__global__ void finalmean_k(const float* __restrict__ T, const float* __restrict__ fw,
                            float* __restrict__ tm){
    __shared__ float part[4][256];
    int b = blockIdx.x;
    int t = threadIdx.x, wave = t >> 6, lane = t & 63;
    float a0 = 0.f, a1 = 0.f, a2 = 0.f, a3 = 0.f;
    for (int s = wave; s < L; s += 4){
        const float* row = T + (size_t)(b * L + s) * D;
        float4 v = *(const float4*)(row + lane * 4);
        float ss = v.x*v.x + v.y*v.y + v.z*v.z + v.w*v.w;
        #pragma unroll
        for (int o = 32; o > 0; o >>= 1) ss += __shfl_xor(ss, o);
        float sc = rsqrtf(ss / (float)D + EPS);
        a0 += v.x * sc; a1 += v.y * sc; a2 += v.z * sc; a3 += v.w * sc;
    }
    *(float4*)&part[wave][lane * 4] = make_float4(a0, a1, a2, a3);
    __syncthreads();
    float v = (part[0][t] + part[1][t] + part[2][t] + part[3][t]) * (1.f / (float)L);
    tm[b * D + t] = v * fw[t];
}

// ---------------- head (fp32)
__global__ void head_k(const float* __restrict__ tm, const float* __restrict__ hw,
                       const float* __restrict__ hb, float* __restrict__ out){
    int i = blockIdx.x * 256 + threadIdx.x;
    if (i >= BATCH * NCLS) return;
    int m = i / NCLS, n = i - m * NCLS;
    float a0 = 0.f, a1 = 0.f, a2 = 0.f, a3 = 0.f;
    const float* tr = tm + m * D;
    #pragma unroll 4
    for (int k = 0; k < D; k += 4){
        a0 = fmaf(tr[k],     hw[(size_t)k * NCLS + n],       a0);
        a1 = fmaf(tr[k + 1], hw[(size_t)(k + 1) * NCLS + n], a1);
        a2 = fmaf(tr[k + 2], hw[(size_t)(k + 2) * NCLS + n], a2);
        a3 = fmaf(tr[k + 3], hw[(size_t)(k + 3) * NCLS + n], a3);
    }
    out[i] = (a0 + a1) + (a2 + a3) + hb[n];
}

extern "C" void kernel_launch(void* const* d_in, const int* in_sizes, int n_in,
                              void* d_out, int out_size, void* d_ws, size_t ws_size,
                              hipStream_t stream){
    (void)in_sizes; (void)n_in; (void)out_size; (void)ws_size;
    const float* x       = (const float*)d_in[0];
    const float* patch_w = (const float*)d_in[1];
    const float* patch_b = (const float*)d_in[2];
    const float* pos     = (const float*)d_in[3];
    const float* norms_w = (const float*)d_in[4];
    const float* final_w = (const float*)d_in[5];
    const float* head_w  = (const float*)d_in[6];
    const float* head_b  = (const float*)d_in[7];
    const float* Win[2]  = {(const float*)d_in[8],  (const float*)d_in[16]};
    const float* cw[2]   = {(const float*)d_in[9],  (const float*)d_in[17]};
    const float* cb[2]   = {(const float*)d_in[10], (const float*)d_in[18]};
    const float* dtb[2]  = {(const float*)d_in[11], (const float*)d_in[19]};
    const float* Alog[2] = {(const float*)d_in[12], (const float*)d_in[20]};
    const float* Dp[2]   = {(const float*)d_in[13], (const float*)d_in[21]};
    const float* gn[2]   = {(const float*)d_in[14], (const float*)d_in[22]};
    const float* Wout[2] = {(const float*)d_in[15], (const float*)d_in[23]};

    float* ws = (float*)d_ws;
    float* t    = ws;                  // 262144
    float* tm   = t    + 262144;       // 4096
    float* zx0  = tm   + 4096;         // 1187840
    float* zx1  = zx0  + 1187840;
    float* xbc0 = zx1  + 1187840;      // 524288 (xs only now)
    float* xbc1 = xbc0 + 524288;
    float* dts0 = xbc1 + 524288;       // 8192 x4
    float* dts1 = dts0 + 8192;
    float* cum0 = dts1 + 8192;
    float* cum1 = cum0 + 8192;
    float* S0   = cum1 + 8192;         // 65536 x2
    float* S1   = S0   + 65536;
    float* y0   = S1   + 65536;        // 524288 x2
    float* y1   = y0   + 524288;
    float* f32end = y1 + 524288;

    ushort_t* ybf0 = (ushort_t*)f32end;          // 524288
    ushort_t* ybf1 = ybf0 + 524288;              // 524288
    ushort_t* wbuf = ybf1 + 524288;              // 1908736
    ushort_t* pw_bf   = wbuf;                    // 196608
    ushort_t* win_bf  = wbuf + 196608;           // 4 x 296960
    ushort_t* wout_bf = wbuf + 1384448;          // 4 x 131072

    const int BL = BATCH * L;   // 1024

    wconv_k<<<dim3(37, 16, 9), 256, 0, stream>>>(
        Win[0], Win[1], Wout[0], Wout[1], patch_w, wbuf);

    gemm_patch_k<<<dim3(4, 16), 256, 0, stream>>>(x, pw_bf, t, patch_b, pos);

    for (int i = 0; i < DEPTH; ++i){
        const float* cw0  = cw[0]   + (size_t)i * CDIM * DCONV;
        const float* cw1  = cw[1]   + (size_t)i * CDIM * DCONV;
        const float* cb0  = cb[0]   + (size_t)i * CDIM;
        const float* cb1  = cb[1]   + (size_t)i * CDIM;
        const float* dtb0 = dtb[0]  + (size_t)i * H;
        const float* dtb1 = dtb[1]  + (size_t)i * H;
        const float* Al0  = Alog[0] + (size_t)i * H;
        const float* Al1  = Alog[1] + (size_t)i * H;
        const float* Dp0  = Dp[0]   + (size_t)i * H;
        const float* Dp1  = Dp[1]   + (size_t)i * H;
        const float* gn0  = gn[0]   + (size_t)i * DIN;
        const float* gn1  = gn[1]   + (size_t)i * DIN;
        const ushort_t* Wi0 = win_bf  + (size_t)(2 * i + 0) * 296960;
        const ushort_t* Wi1 = win_bf  + (size_t)(2 * i + 1) * 296960;
        const ushort_t* Wo0 = wout_bf + (size_t)(2 * i + 0) * 131072;
        const ushort_t* Wo1 = wout_bf + (size_t)(2 * i + 1) * 131072;

        gemm_in_k<<<dim3(19, 16, 2), 256, 0, stream>>>(
            t, norms_w + i * D, Wi0, Wi1, zx0, zx1);
        scanprep_k<<<dim3(2, BATCH), 512, 0, stream>>>(
            zx0, zx1, cw0, cw1, cb0, cb1, dtb0, dtb1, Al0, Al1,
            xbc0, xbc1, dts0, dts1, cum0, cum1, S0, S1);
        yscan_k<<<dim3(H, BATCH, 2), 256, 0, stream>>>(
            S0, S1, xbc0, xbc1, dts0, dts1, cum0, cum1, Dp0, Dp1, y0, y1);
        gate_rmsnorm_k<<<dim3(BL, 2), 256, 0, stream>>>(
            y0, y1, zx0, zx1, gn0, gn1, ybf0, ybf1);
        gemm_out_k<<<dim3(4, 16), 256, 0, stream>>>(ybf0, ybf1, Wo0, Wo1, t);
    }

    finalmean_k<<<BATCH, 256, 0, stream>>>(t, final_w, tm);
    head_k<<<(BATCH * NCLS + 255) / 256, 256, 0, stream>>>(
        tm, head_w, head_b, (float*)d_out);
}

// Round 5
// 158.063 us; speedup vs baseline: 2.2207x; 2.2207x over previous
//
#include <hip/hip_runtime.h>
#include <hip/hip_bf16.h>
#include <math.h>

#define IMG 128
#define PATCH 16
#define L 64
#define D 256
#define DIN 512
#define DH 64
#define H 8
#define NSTATE 64
#define DCONV 4
#define DEPTH 2
#define NCLS 1000
#define BATCH 16
#define DINPROJ 1160   // 2*DIN + 2*N + H
#define CDIM 640       // DIN + 2*N
#define EPS 1e-6f

typedef __attribute__((ext_vector_type(8))) short short8;
typedef __attribute__((ext_vector_type(4))) float f32x4;
typedef __attribute__((ext_vector_type(4))) unsigned short us4;
typedef unsigned short ushort_t;

__device__ __forceinline__ int snake_tok(int s){
    int r = s >> 3, c = s & 7;
    return (r & 1) ? (r * 8 + (7 - c)) : (r * 8 + c);
}
__device__ __forceinline__ float silu_f(float x){ return x / (1.f + expf(-x)); }
__device__ __forceinline__ float softplus_f(float x){ return x > 20.f ? x : log1pf(expf(x)); }
__device__ __forceinline__ ushort_t f2b(float f){
    __hip_bfloat16 h = __float2bfloat16(f);
    return *(ushort_t*)&h;
}

__device__ __forceinline__ float block_sum256(float v){
    __shared__ float sm[4];
    #pragma unroll
    for (int o = 32; o > 0; o >>= 1) v += __shfl_down(v, o);
    if ((threadIdx.x & 63) == 0) sm[threadIdx.x >> 6] = v;
    __syncthreads();
    return sm[0] + sm[1] + sm[2] + sm[3];
}

// ---------------- weight convert: Win/Wout transposed to [N][K] bf16; patch_w copied
__global__ void wconv_k(const float* __restrict__ Win0, const float* __restrict__ Win1,
                        const float* __restrict__ Wout0, const float* __restrict__ Wout1,
                        const float* __restrict__ pw, ushort_t* __restrict__ wbuf){
    int z = blockIdx.z;
    if (z == 8){
        int id = (blockIdx.y * 37 + blockIdx.x) * 256 + threadIdx.x;
        for (; id < 196608; id += 37 * 16 * 256)
            wbuf[id] = f2b(pw[id]);
        return;
    }
    __shared__ float sm[32][33];
    int R, C; const float* src; ushort_t* dst;
    if (z < 4){
        int layer = z >> 1, dir = z & 1;
        src = (dir ? Win1 : Win0) + (size_t)layer * D * DINPROJ;
        dst = wbuf + 196608 + (size_t)z * 296960;
        R = D; C = DINPROJ;
    } else {
        int zz = z - 4, layer = zz >> 1, dir = zz & 1;
        src = (dir ? Wout1 : Wout0) + (size_t)layer * DIN * D;
        dst = wbuf + 1384448 + (size_t)zz * 131072;
        R = DIN; C = D;
    }
    int ctiles = (C + 31) >> 5, rtiles = R >> 5;
    if (blockIdx.x >= ctiles || blockIdx.y >= rtiles) return;
    int c0 = blockIdx.x * 32, r0 = blockIdx.y * 32;
    int tx = threadIdx.x & 31, ty = threadIdx.x >> 5;
    #pragma unroll
    for (int k = 0; k < 4; ++k){
        int r = r0 + ty + 8 * k, c = c0 + tx;
        sm[ty + 8 * k][tx] = (c < C) ? src[(size_t)r * C + c] : 0.f;
    }
    __syncthreads();
    #pragma unroll
    for (int k = 0; k < 4; ++k){
        int dr = c0 + ty + 8 * k, dc = r0 + tx;
        if (dr < C) dst[(size_t)dr * R + dc] = f2b(sm[tx][ty + 8 * k]);
    }
}

// ---------------- patch GEMM with fused patchify gather + bias/pos epilogue
__global__ __launch_bounds__(256) void gemm_patch_k(
    const float* __restrict__ x, const ushort_t* __restrict__ Bw,
    float* __restrict__ C, const float* __restrict__ pb, const float* __restrict__ pos)
{
    __shared__ __align__(16) ushort_t As[2][64][40];
    __shared__ __align__(16) ushort_t Bs[2][64][40];
    const int t = threadIdx.x;
    const int n0 = blockIdx.x * 64;
    const int b  = blockIdx.y;              // m0 = b*64
    const int lrow = t >> 2, lc8 = (t & 3) * 8;
    const int tok = snake_tok(lrow), gy = tok >> 3, gx = tok & 7;
    const float* xb = x + (size_t)b * 3 * IMG * IMG;
    const int wave = t >> 6, lane = t & 63;
    const int wm = (wave >> 1) * 32, wn = (wave & 1) * 32;
    const int fro = lane & 15, fk = (lane >> 4) * 8;

    f32x4 acc[2][2];
    #pragma unroll
    for (int i = 0; i < 2; ++i)
        #pragma unroll
        for (int j = 0; j < 2; ++j) acc[i][j] = (f32x4){0.f,0.f,0.f,0.f};

    short8 areg; float4 breg;
    auto gload = [&](int kk){
        int k = kk + lc8;
        int c = k >> 8, rem = k & 255, py = rem >> 4, px = rem & 15;
        const float* src = xb + ((size_t)c * IMG + gy * PATCH + py) * IMG + gx * PATCH + px;
        float4 a0 = *(const float4*)(src);
        float4 a1 = *(const float4*)(src + 4);
        ushort_t tmp[8] = {f2b(a0.x),f2b(a0.y),f2b(a0.z),f2b(a0.w),
                           f2b(a1.x),f2b(a1.y),f2b(a1.z),f2b(a1.w)};
        areg = *(short8*)tmp;
        breg = *(const float4*)(Bw + (size_t)(n0 + lrow) * 768 + kk + lc8);
    };
    auto sstore = [&](int buf){
        *(short8*)&As[buf][lrow][lc8] = areg;
        *(float4*)&Bs[buf][lrow][lc8] = breg;
    };

    const int nk = 768 / 32;
    gload(0); sstore(0);
    __syncthreads();
    for (int kt = 0; kt < nk; ++kt){
        const int buf = kt & 1;
        if (kt + 1 < nk) gload((kt + 1) * 32);
        short8 af[2], bfr[2];
        af[0]  = *(const short8*)&As[buf][wm + fro][fk];
        af[1]  = *(const short8*)&As[buf][wm + 16 + fro][fk];
        bfr[0] = *(const short8*)&Bs[buf][wn + fro][fk];
        bfr[1] = *(const short8*)&Bs[buf][wn + 16 + fro][fk];
        #pragma unroll
        for (int i = 0; i < 2; ++i)
            #pragma unroll
            for (int j = 0; j < 2; ++j)
                acc[i][j] = __builtin_amdgcn_mfma_f32_16x16x32_bf16(af[i], bfr[j], acc[i][j], 0, 0, 0);
        if (kt + 1 < nk) sstore(buf ^ 1);
        __syncthreads();
    }
    #pragma unroll
    for (int i = 0; i < 2; ++i){
        #pragma unroll
        for (int j = 0; j < 2; ++j){
            int col = n0 + wn + j * 16 + (lane & 15);
            #pragma unroll
            for (int r = 0; r < 4; ++r){
                int srow = wm + i * 16 + (lane >> 4) * 4 + r;   // token s
                C[(size_t)(b * 64 + srow) * D + col] =
                    acc[i][j][r] + pb[col] + pos[snake_tok(srow) * D + col];
            }
        }
    }
}

// ---------------- in-proj GEMM with fused rmsnorm prologue.
__global__ __launch_bounds__(256) void gemm_in_k(
    const float* __restrict__ T, const float* __restrict__ nw,
    const ushort_t* __restrict__ B0, const ushort_t* __restrict__ B1,
    float* __restrict__ C0, float* __restrict__ C1)
{
    __shared__ __align__(16) ushort_t As[64][264];
    __shared__ __align__(16) ushort_t Bs[2][64][40];
    const int dir = blockIdx.z;
    const ushort_t* __restrict__ Bw = dir ? B1 : B0;
    float* __restrict__ C = dir ? C1 : C0;
    const int t = threadIdx.x;
    const int m0 = blockIdx.y * 64, n0 = blockIdx.x * 64;
    const int arow = t >> 2;
    const int wave = t >> 6, lane = t & 63;
    const int wm = (wave >> 1) * 32, wn = (wave & 1) * 32;
    const int fro = lane & 15, fk = (lane >> 4) * 8;

    {
        const float* src = T + (size_t)(m0 + arow) * D;
        float ss = 0.f;
        #pragma unroll
        for (int i = 0; i < 16; ++i){
            int c = (t & 3) * 4 + i * 16;
            float4 v = *(const float4*)(src + c);
            ss += v.x*v.x + v.y*v.y + v.z*v.z + v.w*v.w;
        }
        ss += __shfl_xor(ss, 1);
        ss += __shfl_xor(ss, 2);
        float sc = rsqrtf(ss * (1.f / (float)D) + EPS);
        #pragma unroll
        for (int i = 0; i < 16; ++i){
            int c = (t & 3) * 4 + i * 16;
            float4 v = *(const float4*)(src + c);
            float4 w = *(const float4*)(nw + c);
            us4 o = {f2b(v.x*sc*w.x), f2b(v.y*sc*w.y), f2b(v.z*sc*w.z), f2b(v.w*sc*w.w)};
            *(us4*)&As[arow][c] = o;
        }
    }
    const int lrow = t >> 2, lc8 = (t & 3) * 8;
    float4 breg;
    auto gloadB = [&](int kk){
        int gn = n0 + lrow;
        if (gn < DINPROJ) breg = *(const float4*)(Bw + (size_t)gn * D + kk + lc8);
        else breg = make_float4(0.f,0.f,0.f,0.f);
    };
    auto sstoreB = [&](int buf){ *(float4*)&Bs[buf][lrow][lc8] = breg; };

    f32x4 acc[2][2];
    #pragma unroll
    for (int i = 0; i < 2; ++i)
        #pragma unroll
        for (int j = 0; j < 2; ++j) acc[i][j] = (f32x4){0.f,0.f,0.f,0.f};

    gloadB(0); sstoreB(0);
    __syncthreads();
    const int nk = D / 32;
    for (int kt = 0; kt < nk; ++kt){
        const int buf = kt & 1;
        if (kt + 1 < nk) gloadB((kt + 1) * 32);
        short8 af[2], bfr[2];
        af[0]  = *(const short8*)&As[wm + fro][kt * 32 + fk];
        af[1]  = *(const short8*)&As[wm + 16 + fro][kt * 32 + fk];
        bfr[0] = *(const short8*)&Bs[buf][wn + fro][fk];
        bfr[1] = *(const short8*)&Bs[buf][wn + 16 + fro][fk];
        #pragma unroll
        for (int i = 0; i < 2; ++i)
            #pragma unroll
            for (int j = 0; j < 2; ++j)
                acc[i][j] = __builtin_amdgcn_mfma_f32_16x16x32_bf16(af[i], bfr[j], acc[i][j], 0, 0, 0);
        if (kt + 1 < nk) sstoreB(buf ^ 1);
        __syncthreads();
    }
    #pragma unroll
    for (int i = 0; i < 2; ++i){
        #pragma unroll
        for (int j = 0; j < 2; ++j){
            int col = n0 + wn + j * 16 + (lane & 15);
            if (col >= DINPROJ) continue;
            #pragma unroll
            for (int r = 0; r < 4; ++r){
                int row = m0 + wm + i * 16 + (lane >> 4) * 4 + r;
                C[(size_t)row * DINPROJ + col] = acc[i][j][r];
            }
        }
    }
}

// ---------------- out-proj GEMM: both dirs accumulated, epilogue t += 0.5*acc
__global__ __launch_bounds__(256) void gemm_out_k(
    const ushort_t* __restrict__ A0, const ushort_t* __restrict__ A1,
    const ushort_t* __restrict__ B0, const ushort_t* __restrict__ B1,
    float* __restrict__ T)
{
    __shared__ __align__(16) ushort_t As[2][64][40];
    __shared__ __align__(16) ushort_t Bs[2][64][40];
    const int t = threadIdx.x;
    const int n0 = blockIdx.x * 64, m0 = blockIdx.y * 64;
    const int lrow = t >> 2, lc8 = (t & 3) * 8;
    const int wave = t >> 6, lane = t & 63;
    const int wm = (wave >> 1) * 32, wn = (wave & 1) * 32;
    const int fro = lane & 15, fk = (lane >> 4) * 8;

    float4 areg, breg;
    auto gload = [&](int tile){
        int d = tile >> 4, kk = (tile & 15) * 32;
        const ushort_t* A = d ? A1 : A0;
        const ushort_t* B = d ? B1 : B0;
        areg = *(const float4*)(A + (size_t)(m0 + lrow) * DIN + kk + lc8);
        breg = *(const float4*)(B + (size_t)(n0 + lrow) * DIN + kk + lc8);
    };
    auto sstore = [&](int buf){
        *(float4*)&As[buf][lrow][lc8] = areg;
        *(float4*)&Bs[buf][lrow][lc8] = breg;
    };

    f32x4 acc[2][2];
    #pragma unroll
    for (int i = 0; i < 2; ++i)
        #pragma unroll
        for (int j = 0; j < 2; ++j) acc[i][j] = (f32x4){0.f,0.f,0.f,0.f};

    const int nk = 32;
    gload(0); sstore(0);
    __syncthreads();
    for (int kt = 0; kt < nk; ++kt){
        const int buf = kt & 1;
        if (kt + 1 < nk) gload(kt + 1);
        short8 af[2], bfr[2];
        af[0]  = *(const short8*)&As[buf][wm + fro][fk];
        af[1]  = *(const short8*)&As[buf][wm + 16 + fro][fk];
        bfr[0] = *(const short8*)&Bs[buf][wn + fro][fk];
        bfr[1] = *(const short8*)&Bs[buf][wn + 16 + fro][fk];
        #pragma unroll
        for (int i = 0; i < 2; ++i)
            #pragma unroll
            for (int j = 0; j < 2; ++j)
                acc[i][j] = __builtin_amdgcn_mfma_f32_16x16x32_bf16(af[i], bfr[j], acc[i][j], 0, 0, 0);
        if (kt + 1 < nk) sstore(buf ^ 1);
        __syncthreads();
    }
    #pragma unroll
    for (int i = 0; i < 2; ++i){
        #pragma unroll
        for (int j = 0; j < 2; ++j){
            int col = n0 + wn + j * 16 + (lane & 15);
            #pragma unroll
            for (int r = 0; r < 4; ++r){
                int row = m0 + wm + i * 16 + (lane >> 4) * 4 + r;
                T[(size_t)row * D + col] += 0.5f * acc[i][j][r];
            }
        }
    }
}

// ---------------- causal depthwise conv + silu; xs -> xy, B/C -> bc; grid (L,B,2)
__global__ void conv_silu_k(const float* __restrict__ zx0, const float* __restrict__ zx1,
                            const float* __restrict__ cw0, const float* __restrict__ cw1,
                            const float* __restrict__ cb0, const float* __restrict__ cb1,
                            float* __restrict__ xy0, float* __restrict__ xy1,
                            float* __restrict__ bc0, float* __restrict__ bc1){
    int dir = blockIdx.z;
    const float* zx = dir ? zx1 : zx0;
    const float* cw = dir ? cw1 : cw0;
    const float* cb = dir ? cb1 : cb0;
    float* xy = dir ? xy1 : xy0;
    float* bc = dir ? bc1 : bc0;
    int s = blockIdx.x, b = blockIdx.y;
    for (int c = threadIdx.x; c < CDIM; c += blockDim.x){
        float acc = cb[c];
        #pragma unroll
        for (int k = 0; k < DCONV; ++k){
            int j = s - (DCONV - 1) + k;
            if (j >= 0){
                int l = dir ? (L - 1 - j) : j;
                acc += cw[c * DCONV + k] * zx[(size_t)(b * L + l) * DINPROJ + DIN + c];
            }
        }
        float v = silu_f(acc);
        if (c < DIN) xy[(size_t)(b * L + s) * DIN + c] = v;
        else         bc[(size_t)(b * L + s) * 128 + (c - DIN)] = v;
    }
}

// ---------------- fused dt-scan + S + mask + PV; grid (H, B, 2), 512 thr
// In-place: reads xs slice from xy, writes y over the same slice.
__global__ __launch_bounds__(512) void yscan2_k(
    const float* __restrict__ zx0, const float* __restrict__ zx1,
    const float* __restrict__ bc0, const float* __restrict__ bc1,
    const float* __restrict__ dtb0, const float* __restrict__ dtb1,
    const float* __restrict__ Al0, const float* __restrict__ Al1,
    const float* __restrict__ Dp0, const float* __restrict__ Dp1,
    float* __restrict__ xy0, float* __restrict__ xy1)
{
    __shared__ float Bc[64][65];
    __shared__ float CX[64][65];     // Cc in phase 1-2, Xs in phase 3-4
    __shared__ float Am[64][65];
    __shared__ float cumS[64], dtS[64];
    const int h = blockIdx.x, b = blockIdx.y, dir = blockIdx.z;
    const float* zx  = dir ? zx1  : zx0;
    const float* bc  = dir ? bc1  : bc0;
    const float* dtb = dir ? dtb1 : dtb0;
    const float* Al  = dir ? Al1  : Al0;
    const float* Dp  = dir ? Dp1  : Dp0;
    float* xy = dir ? xy1 : xy0;
    const int t = threadIdx.x;

    if (t < 64){   // wave 0: dt + prefix scan for this (b,h)
        int s = t, l = dir ? (L - 1 - s) : s;
        float xr = zx[(size_t)(b * L + l) * DINPROJ + DIN + CDIM + h] + dtb[h];
        float dt = softplus_f(xr);
        float val = -expf(Al[h]) * dt;
        #pragma unroll
        for (int o = 1; o < 64; o <<= 1){
            float u = __shfl_up(val, o);
            if (t >= o) val += u;
        }
        cumS[s] = val; dtS[s] = dt;
    }
    for (int i = t; i < 4096; i += 512){
        int s = i >> 6, n = i & 63;
        Bc[s][n] = bc[(size_t)(b * L + s) * 128 + n];
        CX[s][n] = bc[(size_t)(b * L + s) * 128 + 64 + n];
    }
    __syncthreads();
    for (int i = t; i < 4096; i += 512){
        int s = i >> 6, j = i & 63;
        float v = 0.f;
        if (j <= s){
            float acc = 0.f;
            #pragma unroll
            for (int n = 0; n < 64; ++n) acc += CX[s][n] * Bc[j][n];
            v = acc * expf(cumS[s] - cumS[j]) * dtS[j];
        }
        Am[s][j] = v;
    }
    __syncthreads();
    for (int i = t; i < 4096; i += 512){
        int j = i >> 6, p = i & 63;
        CX[j][p] = xy[(size_t)(b * L + j) * DIN + h * DH + p];
    }
    __syncthreads();
    float dp = Dp[h];
    for (int i = t; i < 4096; i += 512){
        int s = i >> 6, p = i & 63;
        float acc = dp * CX[s][p];
        #pragma unroll
        for (int j = 0; j < 64; ++j) acc += Am[s][j] * CX[j][p];
        int l = dir ? (L - 1 - s) : s;
        xy[(size_t)(b * L + l) * DIN + h * DH + p] = acc;
    }
}

// ---------------- ybf = bf16(rmsnorm(y * silu(z), gn)); grid (BL, 2)
__global__ void gate_rmsnorm_k(const float* __restrict__ y0, const float* __restrict__ y1,
                               const float* __restrict__ zx0, const float* __restrict__ zx1,
                               const float* __restrict__ gn0, const float* __restrict__ gn1,
                               ushort_t* __restrict__ ybf0, ushort_t* __restrict__ ybf1){
    int dir = blockIdx.y;
    const float* y = dir ? y1 : y0;
    const float* zx = dir ? zx1 : zx0;
    const float* gn = dir ? gn1 : gn0;
    ushort_t* ybf = dir ? ybf1 : ybf0;
    int row = blockIdx.x;
    float g[2]; float ss = 0.f;
    #pragma unroll
    for (int r = 0; r < 2; ++r){
        int c = threadIdx.x + 256 * r;
        float z = zx[(size_t)row * DINPROJ + c];
        float val = y[(size_t)row * DIN + c] * silu_f(z);
        g[r] = val; ss += val * val;
    }
    float tot = block_sum256(ss);
    float sc = rsqrtf(tot / (float)DIN + EPS);
    #pragma unroll
    for (int r = 0; r < 2; ++r){
        int c = threadIdx.x + 256 * r;
        ybf[(size_t)row * DIN + c] = f2b(g[r] * sc * gn[c]);
    }
}

// ---------------- fused final rmsnorm + mean over L; grid (B), 1024 thr
__global__ __launch_bounds__(1024) void finalmean_k(const float* __restrict__ T,
                                                    const float* __restrict__ fw,
                                                    float* __restrict__ tm){
    __shared__ float part[16][256];
    int b = blockIdx.x;
    int t = threadIdx.x, wave = t >> 6, lane = t & 63;
    float a0 = 0.f, a1 = 0.f, a2 = 0.f, a3 = 0.f;
    for (int s = wave; s < L; s += 16){
        const float* row = T + (size_t)(b * L + s) * D;
        float4 v = *(const float4*)(row + lane * 4);
        float ss = v.x*v.x + v.y*v.y + v.z*v.z + v.w*v.w;
        #pragma unroll
        for (int o = 32; o > 0; o >>= 1) ss += __shfl_xor(ss, o);
        float sc = rsqrtf(ss / (float)D + EPS);
        a0 += v.x * sc; a1 += v.y * sc; a2 += v.z * sc; a3 += v.w * sc;
    }
    *(float4*)&part[wave][lane * 4] = make_float4(a0, a1, a2, a3);
    __syncthreads();
    if (t < 256){
        float v = 0.f;
        #pragma unroll
        for (int w = 0; w < 16; ++w) v += part[w][t];
        tm[b * D + t] = v * (1.f / (float)L) * fw[t];
    }
}

// ---------------- head (fp32)
__global__ void head_k(const float* __restrict__ tm, const float* __restrict__ hw,
                       const float* __restrict__ hb, float* __restrict__ out){
    int i = blockIdx.x * 256 + threadIdx.x;
    if (i >= BATCH * NCLS) return;
    int m = i / NCLS, n = i - m * NCLS;
    float a0 = 0.f, a1 = 0.f, a2 = 0.f, a3 = 0.f;
    const float* tr = tm + m * D;
    #pragma unroll 4
    for (int k = 0; k < D; k += 4){
        a0 = fmaf(tr[k],     hw[(size_t)k * NCLS + n],       a0);
        a1 = fmaf(tr[k + 1], hw[(size_t)(k + 1) * NCLS + n], a1);
        a2 = fmaf(tr[k + 2], hw[(size_t)(k + 2) * NCLS + n], a2);
        a3 = fmaf(tr[k + 3], hw[(size_t)(k + 3) * NCLS + n], a3);
    }
    out[i] = (a0 + a1) + (a2 + a3) + hb[n];
}

extern "C" void kernel_launch(void* const* d_in, const int* in_sizes, int n_in,
                              void* d_out, int out_size, void* d_ws, size_t ws_size,
                              hipStream_t stream){
    (void)in_sizes; (void)n_in; (void)out_size; (void)ws_size;
    const float* x       = (const float*)d_in[0];
    const float* patch_w = (const float*)d_in[1];
    const float* patch_b = (const float*)d_in[2];
    const float* pos     = (const float*)d_in[3];
    const float* norms_w = (const float*)d_in[4];
    const float* final_w = (const float*)d_in[5];
    const float* head_w  = (const float*)d_in[6];
    const float* head_b  = (const float*)d_in[7];
    const float* Win[2]  = {(const float*)d_in[8],  (const float*)d_in[16]};
    const float* cw[2]   = {(const float*)d_in[9],  (const float*)d_in[17]};
    const float* cb[2]   = {(const float*)d_in[10], (const float*)d_in[18]};
    const float* dtb[2]  = {(const float*)d_in[11], (const float*)d_in[19]};
    const float* Alog[2] = {(const float*)d_in[12], (const float*)d_in[20]};
    const float* Dp[2]   = {(const float*)d_in[13], (const float*)d_in[21]};
    const float* gn[2]   = {(const float*)d_in[14], (const float*)d_in[22]};
    const float* Wout[2] = {(const float*)d_in[15], (const float*)d_in[23]};

    float* ws = (float*)d_ws;
    float* t    = ws;                  // 262144
    float* tm   = t    + 262144;       // 4096
    float* zx0  = tm   + 4096;         // 1187840
    float* zx1  = zx0  + 1187840;
    float* xy0  = zx1  + 1187840;      // 524288 (xs, overwritten in-place by y)
    float* xy1  = xy0  + 524288;
    float* bcb0 = xy1  + 524288;       // 131072 (B,C compact)
    float* bcb1 = bcb0 + 131072;
    float* f32end = bcb1 + 131072;

    ushort_t* ybf0 = (ushort_t*)f32end;          // 524288
    ushort_t* ybf1 = ybf0 + 524288;              // 524288
    ushort_t* wbuf = ybf1 + 524288;              // 1908736
    ushort_t* pw_bf   = wbuf;                    // 196608
    ushort_t* win_bf  = wbuf + 196608;           // 4 x 296960
    ushort_t* wout_bf = wbuf + 1384448;          // 4 x 131072

    const int BL = BATCH * L;   // 1024

    wconv_k<<<dim3(37, 16, 9), 256, 0, stream>>>(
        Win[0], Win[1], Wout[0], Wout[1], patch_w, wbuf);

    gemm_patch_k<<<dim3(4, 16), 256, 0, stream>>>(x, pw_bf, t, patch_b, pos);

    for (int i = 0; i < DEPTH; ++i){
        const float* cw0  = cw[0]   + (size_t)i * CDIM * DCONV;
        const float* cw1  = cw[1]   + (size_t)i * CDIM * DCONV;
        const float* cb0  = cb[0]   + (size_t)i * CDIM;
        const float* cb1  = cb[1]   + (size_t)i * CDIM;
        const float* dtb0 = dtb[0]  + (size_t)i * H;
        const float* dtb1 = dtb[1]  + (size_t)i * H;
        const float* Al0  = Alog[0] + (size_t)i * H;
        const float* Al1  = Alog[1] + (size_t)i * H;
        const float* Dp0  = Dp[0]   + (size_t)i * H;
        const float* Dp1  = Dp[1]   + (size_t)i * H;
        const float* gn0  = gn[0]   + (size_t)i * DIN;
        const float* gn1  = gn[1]   + (size_t)i * DIN;
        const ushort_t* Wi0 = win_bf  + (size_t)(2 * i + 0) * 296960;
        const ushort_t* Wi1 = win_bf  + (size_t)(2 * i + 1) * 296960;
        const ushort_t* Wo0 = wout_bf + (size_t)(2 * i + 0) * 131072;
        const ushort_t* Wo1 = wout_bf + (size_t)(2 * i + 1) * 131072;

        gemm_in_k<<<dim3(19, 16, 2), 256, 0, stream>>>(
            t, norms_w + i * D, Wi0, Wi1, zx0, zx1);
        conv_silu_k<<<dim3(L, BATCH, 2), 256, 0, stream>>>(
            zx0, zx1, cw0, cw1, cb0, cb1, xy0, xy1, bcb0, bcb1);
        yscan2_k<<<dim3(H, BATCH, 2), 512, 0, stream>>>(
            zx0, zx1, bcb0, bcb1, dtb0, dtb1, Al0, Al1, Dp0, Dp1, xy0, xy1);
        gate_rmsnorm_k<<<dim3(BL, 2), 256, 0, stream>>>(
            xy0, xy1, zx0, zx1, gn0, gn1, ybf0, ybf1);
        gemm_out_k<<<dim3(4, 16), 256, 0, stream>>>(ybf0, ybf1, Wo0, Wo1, t);
    }

    finalmean_k<<<BATCH, 1024, 0, stream>>>(t, final_w, tm);
    head_k<<<(BATCH * NCLS + 255) / 256, 256, 0, stream>>>(
        tm, head_w, head_b, (float*)d_out);
}

// Round 6
// 143.765 us; speedup vs baseline: 2.4416x; 1.0995x over previous
//
#include <hip/hip_runtime.h>
#include <hip/hip_bf16.h>
#include <math.h>

#define IMG 128
#define PATCH 16
#define L 64
#define D 256
#define DIN 512
#define DH 64
#define H 8
#define NSTATE 64
#define DCONV 4
#define DEPTH 2
#define NCLS 1000
#define BATCH 16
#define DINPROJ 1160   // 2*DIN + 2*N + H
#define CDIM 640       // DIN + 2*N
#define EPS 1e-6f

typedef __attribute__((ext_vector_type(8))) short short8;
typedef __attribute__((ext_vector_type(4))) float f32x4;
typedef __attribute__((ext_vector_type(4))) unsigned short us4;
typedef unsigned short ushort_t;

__device__ __forceinline__ int snake_tok(int s){
    int r = s >> 3, c = s & 7;
    return (r & 1) ? (r * 8 + (7 - c)) : (r * 8 + c);
}
__device__ __forceinline__ float silu_f(float x){ return x / (1.f + expf(-x)); }
__device__ __forceinline__ float softplus_f(float x){ return x > 20.f ? x : log1pf(expf(x)); }
__device__ __forceinline__ ushort_t f2b(float f){
    __hip_bfloat16 h = __float2bfloat16(f);
    return *(ushort_t*)&h;
}

__device__ __forceinline__ float block_sum256(float v){
    __shared__ float sm[4];
    #pragma unroll
    for (int o = 32; o > 0; o >>= 1) v += __shfl_down(v, o);
    if ((threadIdx.x & 63) == 0) sm[threadIdx.x >> 6] = v;
    __syncthreads();
    return sm[0] + sm[1] + sm[2] + sm[3];
}

// ---------------- weight convert: Win/Wout transposed to [N][K] bf16; patch_w copied
__global__ void wconv_k(const float* __restrict__ Win0, const float* __restrict__ Win1,
                        const float* __restrict__ Wout0, const float* __restrict__ Wout1,
                        const float* __restrict__ pw, ushort_t* __restrict__ wbuf){
    int z = blockIdx.z;
    if (z == 8){
        int id = (blockIdx.y * 37 + blockIdx.x) * 256 + threadIdx.x;
        for (; id < 196608; id += 37 * 16 * 256)
            wbuf[id] = f2b(pw[id]);
        return;
    }
    __shared__ float sm[32][33];
    int R, C; const float* src; ushort_t* dst;
    if (z < 4){
        int layer = z >> 1, dir = z & 1;
        src = (dir ? Win1 : Win0) + (size_t)layer * D * DINPROJ;
        dst = wbuf + 196608 + (size_t)z * 296960;
        R = D; C = DINPROJ;
    } else {
        int zz = z - 4, layer = zz >> 1, dir = zz & 1;
        src = (dir ? Wout1 : Wout0) + (size_t)layer * DIN * D;
        dst = wbuf + 1384448 + (size_t)zz * 131072;
        R = DIN; C = D;
    }
    int ctiles = (C + 31) >> 5, rtiles = R >> 5;
    if (blockIdx.x >= ctiles || blockIdx.y >= rtiles) return;
    int c0 = blockIdx.x * 32, r0 = blockIdx.y * 32;
    int tx = threadIdx.x & 31, ty = threadIdx.x >> 5;
    #pragma unroll
    for (int k = 0; k < 4; ++k){
        int r = r0 + ty + 8 * k, c = c0 + tx;
        sm[ty + 8 * k][tx] = (c < C) ? src[(size_t)r * C + c] : 0.f;
    }
    __syncthreads();
    #pragma unroll
    for (int k = 0; k < 4; ++k){
        int dr = c0 + ty + 8 * k, dc = r0 + tx;
        if (dr < C) dst[(size_t)dr * R + dc] = f2b(sm[tx][ty + 8 * k]);
    }
}

// ---------------- patch GEMM, split-K=8 (96 K each); partials out
__global__ __launch_bounds__(256) void gemm_patch_k(
    const float* __restrict__ x, const ushort_t* __restrict__ Bw,
    float* __restrict__ part)
{
    __shared__ __align__(16) ushort_t As[2][64][40];
    __shared__ __align__(16) ushort_t Bs[2][64][40];
    const int t = threadIdx.x;
    const int n0 = blockIdx.x * 64;
    const int b  = blockIdx.y;
    const int split = blockIdx.z;
    const int kbase = split * 96;
    const int lrow = t >> 2, lc8 = (t & 3) * 8;
    const int tok = snake_tok(lrow), gy = tok >> 3, gx = tok & 7;
    const float* xb = x + (size_t)b * 3 * IMG * IMG;
    const int wave = t >> 6, lane = t & 63;
    const int wm = (wave >> 1) * 32, wn = (wave & 1) * 32;
    const int fro = lane & 15, fk = (lane >> 4) * 8;

    f32x4 acc[2][2];
    #pragma unroll
    for (int i = 0; i < 2; ++i)
        #pragma unroll
        for (int j = 0; j < 2; ++j) acc[i][j] = (f32x4){0.f,0.f,0.f,0.f};

    short8 areg; float4 breg;
    auto gload = [&](int kk){
        int k = kk + lc8;
        int c = k >> 8, rem = k & 255, py = rem >> 4, px = rem & 15;
        const float* src = xb + ((size_t)c * IMG + gy * PATCH + py) * IMG + gx * PATCH + px;
        float4 a0 = *(const float4*)(src);
        float4 a1 = *(const float4*)(src + 4);
        ushort_t tmp[8] = {f2b(a0.x),f2b(a0.y),f2b(a0.z),f2b(a0.w),
                           f2b(a1.x),f2b(a1.y),f2b(a1.z),f2b(a1.w)};
        areg = *(short8*)tmp;
        breg = *(const float4*)(Bw + (size_t)(n0 + lrow) * 768 + kk + lc8);
    };
    auto sstore = [&](int buf){
        *(short8*)&As[buf][lrow][lc8] = areg;
        *(float4*)&Bs[buf][lrow][lc8] = breg;
    };

    const int nk = 3;
    gload(kbase); sstore(0);
    __syncthreads();
    for (int kt = 0; kt < nk; ++kt){
        const int buf = kt & 1;
        if (kt + 1 < nk) gload(kbase + (kt + 1) * 32);
        short8 af[2], bfr[2];
        af[0]  = *(const short8*)&As[buf][wm + fro][fk];
        af[1]  = *(const short8*)&As[buf][wm + 16 + fro][fk];
        bfr[0] = *(const short8*)&Bs[buf][wn + fro][fk];
        bfr[1] = *(const short8*)&Bs[buf][wn + 16 + fro][fk];
        #pragma unroll
        for (int i = 0; i < 2; ++i)
            #pragma unroll
            for (int j = 0; j < 2; ++j)
                acc[i][j] = __builtin_amdgcn_mfma_f32_16x16x32_bf16(af[i], bfr[j], acc[i][j], 0, 0, 0);
        if (kt + 1 < nk) sstore(buf ^ 1);
        __syncthreads();
    }
    float* Cp = part + (size_t)split * (BATCH * L * D);
    #pragma unroll
    for (int i = 0; i < 2; ++i){
        #pragma unroll
        for (int j = 0; j < 2; ++j){
            int col = n0 + wn + j * 16 + (lane & 15);
            #pragma unroll
            for (int r = 0; r < 4; ++r){
                int srow = wm + i * 16 + (lane >> 4) * 4 + r;
                Cp[(size_t)(b * 64 + srow) * D + col] = acc[i][j][r];
            }
        }
    }
}

// ---------------- patch reduce: t = sum(8 partials) + pb + pos
__global__ void patch_red_k(const float* __restrict__ part, const float* __restrict__ pb,
                            const float* __restrict__ pos, float* __restrict__ t){
    int i = blockIdx.x * 256 + threadIdx.x;      // B*L*D
    int d = i & (D - 1), s = (i >> 8) & (L - 1);
    float v = 0.f;
    #pragma unroll
    for (int r = 0; r < 8; ++r) v += part[i + r * (BATCH * L * D)];
    t[i] = v + pb[d] + pos[snake_tok(s) * D + d];
}

// ---------------- in-proj GEMM with fused rmsnorm prologue.
__global__ __launch_bounds__(256) void gemm_in_k(
    const float* __restrict__ T, const float* __restrict__ nw,
    const ushort_t* __restrict__ B0, const ushort_t* __restrict__ B1,
    float* __restrict__ C0, float* __restrict__ C1)
{
    __shared__ __align__(16) ushort_t As[64][264];
    __shared__ __align__(16) ushort_t Bs[2][64][40];
    const int dir = blockIdx.z;
    const ushort_t* __restrict__ Bw = dir ? B1 : B0;
    float* __restrict__ C = dir ? C1 : C0;
    const int t = threadIdx.x;
    const int m0 = blockIdx.y * 64, n0 = blockIdx.x * 64;
    const int arow = t >> 2;
    const int wave = t >> 6, lane = t & 63;
    const int wm = (wave >> 1) * 32, wn = (wave & 1) * 32;
    const int fro = lane & 15, fk = (lane >> 4) * 8;

    {
        const float* src = T + (size_t)(m0 + arow) * D;
        float ss = 0.f;
        #pragma unroll
        for (int i = 0; i < 16; ++i){
            int c = (t & 3) * 4 + i * 16;
            float4 v = *(const float4*)(src + c);
            ss += v.x*v.x + v.y*v.y + v.z*v.z + v.w*v.w;
        }
        ss += __shfl_xor(ss, 1);
        ss += __shfl_xor(ss, 2);
        float sc = rsqrtf(ss * (1.f / (float)D) + EPS);
        #pragma unroll
        for (int i = 0; i < 16; ++i){
            int c = (t & 3) * 4 + i * 16;
            float4 v = *(const float4*)(src + c);
            float4 w = *(const float4*)(nw + c);
            us4 o = {f2b(v.x*sc*w.x), f2b(v.y*sc*w.y), f2b(v.z*sc*w.z), f2b(v.w*sc*w.w)};
            *(us4*)&As[arow][c] = o;
        }
    }
    const int lrow = t >> 2, lc8 = (t & 3) * 8;
    float4 breg;
    auto gloadB = [&](int kk){
        int gn = n0 + lrow;
        if (gn < DINPROJ) breg = *(const float4*)(Bw + (size_t)gn * D + kk + lc8);
        else breg = make_float4(0.f,0.f,0.f,0.f);
    };
    auto sstoreB = [&](int buf){ *(float4*)&Bs[buf][lrow][lc8] = breg; };

    f32x4 acc[2][2];
    #pragma unroll
    for (int i = 0; i < 2; ++i)
        #pragma unroll
        for (int j = 0; j < 2; ++j) acc[i][j] = (f32x4){0.f,0.f,0.f,0.f};

    gloadB(0); sstoreB(0);
    __syncthreads();
    const int nk = D / 32;
    for (int kt = 0; kt < nk; ++kt){
        const int buf = kt & 1;
        if (kt + 1 < nk) gloadB((kt + 1) * 32);
        short8 af[2], bfr[2];
        af[0]  = *(const short8*)&As[wm + fro][kt * 32 + fk];
        af[1]  = *(const short8*)&As[wm + 16 + fro][kt * 32 + fk];
        bfr[0] = *(const short8*)&Bs[buf][wn + fro][fk];
        bfr[1] = *(const short8*)&Bs[buf][wn + 16 + fro][fk];
        #pragma unroll
        for (int i = 0; i < 2; ++i)
            #pragma unroll
            for (int j = 0; j < 2; ++j)
                acc[i][j] = __builtin_amdgcn_mfma_f32_16x16x32_bf16(af[i], bfr[j], acc[i][j], 0, 0, 0);
        if (kt + 1 < nk) sstoreB(buf ^ 1);
        __syncthreads();
    }
    #pragma unroll
    for (int i = 0; i < 2; ++i){
        #pragma unroll
        for (int j = 0; j < 2; ++j){
            int col = n0 + wn + j * 16 + (lane & 15);
            if (col >= DINPROJ) continue;
            #pragma unroll
            for (int r = 0; r < 4; ++r){
                int row = m0 + wm + i * 16 + (lane >> 4) * 4 + r;
                C[(size_t)row * DINPROJ + col] = acc[i][j][r];
            }
        }
    }
}

// ---------------- out-proj GEMM split-K=8 over (dir, quarter); partials out
__global__ __launch_bounds__(256) void gemm_out_k(
    const ushort_t* __restrict__ A0, const ushort_t* __restrict__ A1,
    const ushort_t* __restrict__ B0, const ushort_t* __restrict__ B1,
    float* __restrict__ part)
{
    __shared__ __align__(16) ushort_t As[2][64][40];
    __shared__ __align__(16) ushort_t Bs[2][64][40];
    const int t = threadIdx.x;
    const int n0 = blockIdx.x * 64, m0 = blockIdx.y * 64;
    const int z = blockIdx.z;
    const int dir = z >> 2;
    const int kbase = (z & 3) * 128;        // 4 tiles of 32
    const ushort_t* __restrict__ A = dir ? A1 : A0;
    const ushort_t* __restrict__ B = dir ? B1 : B0;
    const int lrow = t >> 2, lc8 = (t & 3) * 8;
    const int wave = t >> 6, lane = t & 63;
    const int wm = (wave >> 1) * 32, wn = (wave & 1) * 32;
    const int fro = lane & 15, fk = (lane >> 4) * 8;

    float4 areg, breg;
    auto gload = [&](int kk){
        areg = *(const float4*)(A + (size_t)(m0 + lrow) * DIN + kk + lc8);
        breg = *(const float4*)(B + (size_t)(n0 + lrow) * DIN + kk + lc8);
    };
    auto sstore = [&](int buf){
        *(float4*)&As[buf][lrow][lc8] = areg;
        *(float4*)&Bs[buf][lrow][lc8] = breg;
    };

    f32x4 acc[2][2];
    #pragma unroll
    for (int i = 0; i < 2; ++i)
        #pragma unroll
        for (int j = 0; j < 2; ++j) acc[i][j] = (f32x4){0.f,0.f,0.f,0.f};

    const int nk = 4;
    gload(kbase); sstore(0);
    __syncthreads();
    for (int kt = 0; kt < nk; ++kt){
        const int buf = kt & 1;
        if (kt + 1 < nk) gload(kbase + (kt + 1) * 32);
        short8 af[2], bfr[2];
        af[0]  = *(const short8*)&As[buf][wm + fro][fk];
        af[1]  = *(const short8*)&As[buf][wm + 16 + fro][fk];
        bfr[0] = *(const short8*)&Bs[buf][wn + fro][fk];
        bfr[1] = *(const short8*)&Bs[buf][wn + 16 + fro][fk];
        #pragma unroll
        for (int i = 0; i < 2; ++i)
            #pragma unroll
            for (int j = 0; j < 2; ++j)
                acc[i][j] = __builtin_amdgcn_mfma_f32_16x16x32_bf16(af[i], bfr[j], acc[i][j], 0, 0, 0);
        if (kt + 1 < nk) sstore(buf ^ 1);
        __syncthreads();
    }
    float* Cp = part + (size_t)z * (BATCH * L * D);
    #pragma unroll
    for (int i = 0; i < 2; ++i){
        #pragma unroll
        for (int j = 0; j < 2; ++j){
            int col = n0 + wn + j * 16 + (lane & 15);
            #pragma unroll
            for (int r = 0; r < 4; ++r){
                int row = m0 + wm + i * 16 + (lane >> 4) * 4 + r;
                Cp[(size_t)row * D + col] = acc[i][j][r];
            }
        }
    }
}

// ---------------- out reduce: t += 0.5 * sum(8 partials)
__global__ void out_red_k(const float* __restrict__ part, float* __restrict__ t){
    int i = blockIdx.x * 256 + threadIdx.x;
    float v = 0.f;
    #pragma unroll
    for (int r = 0; r < 8; ++r) v += part[i + r * (BATCH * L * D)];
    t[i] += 0.5f * v;
}

// ---------------- causal depthwise conv + silu; xs -> xy, B/C -> bc; grid (L,B,2)
__global__ void conv_silu_k(const float* __restrict__ zx0, const float* __restrict__ zx1,
                            const float* __restrict__ cw0, const float* __restrict__ cw1,
                            const float* __restrict__ cb0, const float* __restrict__ cb1,
                            float* __restrict__ xy0, float* __restrict__ xy1,
                            float* __restrict__ bc0, float* __restrict__ bc1){
    int dir = blockIdx.z;
    const float* zx = dir ? zx1 : zx0;
    const float* cw = dir ? cw1 : cw0;
    const float* cb = dir ? cb1 : cb0;
    float* xy = dir ? xy1 : xy0;
    float* bc = dir ? bc1 : bc0;
    int s = blockIdx.x, b = blockIdx.y;
    for (int c = threadIdx.x; c < CDIM; c += blockDim.x){
        float acc = cb[c];
        #pragma unroll
        for (int k = 0; k < DCONV; ++k){
            int j = s - (DCONV - 1) + k;
            if (j >= 0){
                int l = dir ? (L - 1 - j) : j;
                acc += cw[c * DCONV + k] * zx[(size_t)(b * L + l) * DINPROJ + DIN + c];
            }
        }
        float v = silu_f(acc);
        if (c < DIN) xy[(size_t)(b * L + s) * DIN + c] = v;
        else         bc[(size_t)(b * L + s) * 128 + (c - DIN)] = v;
    }
}

// ---------------- fused dt-scan + S + mask + PV; grid (H, B, 2), 512 thr
__global__ __launch_bounds__(512) void yscan2_k(
    const float* __restrict__ zx0, const float* __restrict__ zx1,
    const float* __restrict__ bc0, const float* __restrict__ bc1,
    const float* __restrict__ dtb0, const float* __restrict__ dtb1,
    const float* __restrict__ Al0, const float* __restrict__ Al1,
    const float* __restrict__ Dp0, const float* __restrict__ Dp1,
    float* __restrict__ xy0, float* __restrict__ xy1)
{
    __shared__ float Bc[64][65];
    __shared__ float CX[64][65];
    __shared__ float Am[64][65];
    __shared__ float cumS[64], dtS[64];
    const int h = blockIdx.x, b = blockIdx.y, dir = blockIdx.z;
    const float* zx  = dir ? zx1  : zx0;
    const float* bc  = dir ? bc1  : bc0;
    const float* dtb = dir ? dtb1 : dtb0;
    const float* Al  = dir ? Al1  : Al0;
    const float* Dp  = dir ? Dp1  : Dp0;
    float* xy = dir ? xy1 : xy0;
    const int t = threadIdx.x;

    if (t < 64){
        int s = t, l = dir ? (L - 1 - s) : s;
        float xr = zx[(size_t)(b * L + l) * DINPROJ + DIN + CDIM + h] + dtb[h];
        float dt = softplus_f(xr);
        float val = -expf(Al[h]) * dt;
        #pragma unroll
        for (int o = 1; o < 64; o <<= 1){
            float u = __shfl_up(val, o);
            if (t >= o) val += u;
        }
        cumS[s] = val; dtS[s] = dt;
    }
    for (int i = t; i < 4096; i += 512){
        int s = i >> 6, n = i & 63;
        Bc[s][n] = bc[(size_t)(b * L + s) * 128 + n];
        CX[s][n] = bc[(size_t)(b * L + s) * 128 + 64 + n];
    }
    __syncthreads();
    for (int i = t; i < 4096; i += 512){
        int s = i >> 6, j = i & 63;
        float v = 0.f;
        if (j <= s){
            float acc = 0.f;
            #pragma unroll
            for (int n = 0; n < 64; ++n) acc += CX[s][n] * Bc[j][n];
            v = acc * expf(cumS[s] - cumS[j]) * dtS[j];
        }
        Am[s][j] = v;
    }
    __syncthreads();
    for (int i = t; i < 4096; i += 512){
        int j = i >> 6, p = i & 63;
        CX[j][p] = xy[(size_t)(b * L + j) * DIN + h * DH + p];
    }
    __syncthreads();
    float dp = Dp[h];
    for (int i = t; i < 4096; i += 512){
        int s = i >> 6, p = i & 63;
        float acc = dp * CX[s][p];
        #pragma unroll
        for (int j = 0; j < 64; ++j) acc += Am[s][j] * CX[j][p];
        int l = dir ? (L - 1 - s) : s;
        xy[(size_t)(b * L + l) * DIN + h * DH + p] = acc;
    }
}

// ---------------- ybf = bf16(rmsnorm(y * silu(z), gn)); grid (BL, 2)
__global__ void gate_rmsnorm_k(const float* __restrict__ y0, const float* __restrict__ y1,
                               const float* __restrict__ zx0, const float* __restrict__ zx1,
                               const float* __restrict__ gn0, const float* __restrict__ gn1,
                               ushort_t* __restrict__ ybf0, ushort_t* __restrict__ ybf1){
    int dir = blockIdx.y;
    const float* y = dir ? y1 : y0;
    const float* zx = dir ? zx1 : zx0;
    const float* gn = dir ? gn1 : gn0;
    ushort_t* ybf = dir ? ybf1 : ybf0;
    int row = blockIdx.x;
    float g[2]; float ss = 0.f;
    #pragma unroll
    for (int r = 0; r < 2; ++r){
        int c = threadIdx.x + 256 * r;
        float z = zx[(size_t)row * DINPROJ + c];
        float val = y[(size_t)row * DIN + c] * silu_f(z);
        g[r] = val; ss += val * val;
    }
    float tot = block_sum256(ss);
    float sc = rsqrtf(tot / (float)DIN + EPS);
    #pragma unroll
    for (int r = 0; r < 2; ++r){
        int c = threadIdx.x + 256 * r;
        ybf[(size_t)row * DIN + c] = f2b(g[r] * sc * gn[c]);
    }
}

// ---------------- fused final rmsnorm + mean over L; grid (B), 1024 thr
__global__ __launch_bounds__(1024) void finalmean_k(const float* __restrict__ T,
                                                    const float* __restrict__ fw,
                                                    float* __restrict__ tm){
    __shared__ float part[16][256];
    int b = blockIdx.x;
    int t = threadIdx.x, wave = t >> 6, lane = t & 63;
    float a0 = 0.f, a1 = 0.f, a2 = 0.f, a3 = 0.f;
    for (int s = wave; s < L; s += 16){
        const float* row = T + (size_t)(b * L + s) * D;
        float4 v = *(const float4*)(row + lane * 4);
        float ss = v.x*v.x + v.y*v.y + v.z*v.z + v.w*v.w;
        #pragma unroll
        for (int o = 32; o > 0; o >>= 1) ss += __shfl_xor(ss, o);
        float sc = rsqrtf(ss / (float)D + EPS);
        a0 += v.x * sc; a1 += v.y * sc; a2 += v.z * sc; a3 += v.w * sc;
    }
    *(float4*)&part[wave][lane * 4] = make_float4(a0, a1, a2, a3);
    __syncthreads();
    if (t < 256){
        float v = 0.f;
        #pragma unroll
        for (int w = 0; w < 16; ++w) v += part[w][t];
        tm[b * D + t] = v * (1.f / (float)L) * fw[t];
    }
}

// ---------------- head split-K=4: partials (grid (63,4))
__global__ void head_k(const float* __restrict__ tm, const float* __restrict__ hw,
                       float* __restrict__ hpart){
    int i = blockIdx.x * 256 + threadIdx.x;
    if (i >= BATCH * NCLS) return;
    int z = blockIdx.y;
    int m = i / NCLS, n = i - m * NCLS;
    int k0 = z * 64;
    float a0 = 0.f, a1 = 0.f, a2 = 0.f, a3 = 0.f;
    const float* tr = tm + m * D + k0;
    const float* hc = hw + (size_t)k0 * NCLS + n;
    #pragma unroll 4
    for (int k = 0; k < 64; k += 4){
        a0 = fmaf(tr[k],     hc[(size_t)k * NCLS],       a0);
        a1 = fmaf(tr[k + 1], hc[(size_t)(k + 1) * NCLS], a1);
        a2 = fmaf(tr[k + 2], hc[(size_t)(k + 2) * NCLS], a2);
        a3 = fmaf(tr[k + 3], hc[(size_t)(k + 3) * NCLS], a3);
    }
    hpart[z * (BATCH * NCLS) + i] = (a0 + a1) + (a2 + a3);
}

// ---------------- head reduce
__global__ void head_red_k(const float* __restrict__ hpart, const float* __restrict__ hb,
                           float* __restrict__ out){
    int i = blockIdx.x * 256 + threadIdx.x;
    if (i >= BATCH * NCLS) return;
    int n = i % NCLS;
    out[i] = hpart[i] + hpart[i + BATCH * NCLS] + hpart[i + 2 * BATCH * NCLS]
           + hpart[i + 3 * BATCH * NCLS] + hb[n];
}

extern "C" void kernel_launch(void* const* d_in, const int* in_sizes, int n_in,
                              void* d_out, int out_size, void* d_ws, size_t ws_size,
                              hipStream_t stream){
    (void)in_sizes; (void)n_in; (void)out_size; (void)ws_size;
    const float* x       = (const float*)d_in[0];
    const float* patch_w = (const float*)d_in[1];
    const float* patch_b = (const float*)d_in[2];
    const float* pos     = (const float*)d_in[3];
    const float* norms_w = (const float*)d_in[4];
    const float* final_w = (const float*)d_in[5];
    const float* head_w  = (const float*)d_in[6];
    const float* head_b  = (const float*)d_in[7];
    const float* Win[2]  = {(const float*)d_in[8],  (const float*)d_in[16]};
    const float* cw[2]   = {(const float*)d_in[9],  (const float*)d_in[17]};
    const float* cb[2]   = {(const float*)d_in[10], (const float*)d_in[18]};
    const float* dtb[2]  = {(const float*)d_in[11], (const float*)d_in[19]};
    const float* Alog[2] = {(const float*)d_in[12], (const float*)d_in[20]};
    const float* Dp[2]   = {(const float*)d_in[13], (const float*)d_in[21]};
    const float* gn[2]   = {(const float*)d_in[14], (const float*)d_in[22]};
    const float* Wout[2] = {(const float*)d_in[15], (const float*)d_in[23]};

    float* ws = (float*)d_ws;
    float* t    = ws;                  // 262144
    float* tm   = t    + 262144;       // 4096
    float* zx0  = tm   + 4096;         // 1187840
    float* zx1  = zx0  + 1187840;
    float* xy0  = zx1  + 1187840;      // 524288 (xs, overwritten in-place by y)
    float* xy1  = xy0  + 524288;
    float* bcb0 = xy1  + 524288;       // 131072
    float* bcb1 = bcb0 + 131072;
    float* f32end = bcb1 + 131072;
    // partial buffers alias dead regions:
    float* part  = zx0;                // patch/out partials: 8*262144 = 2097152 <= 2*1187840
    float* hpart = xy0;                // head partials: 4*16000 = 64000

    ushort_t* ybf0 = (ushort_t*)f32end;          // 524288
    ushort_t* ybf1 = ybf0 + 524288;              // 524288
    ushort_t* wbuf = ybf1 + 524288;              // 1908736
    ushort_t* pw_bf   = wbuf;                    // 196608
    ushort_t* win_bf  = wbuf + 196608;           // 4 x 296960
    ushort_t* wout_bf = wbuf + 1384448;          // 4 x 131072

    const int BL = BATCH * L;   // 1024

    wconv_k<<<dim3(37, 16, 9), 256, 0, stream>>>(
        Win[0], Win[1], Wout[0], Wout[1], patch_w, wbuf);

    gemm_patch_k<<<dim3(4, 16, 8), 256, 0, stream>>>(x, pw_bf, part);
    patch_red_k<<<BL, 256, 0, stream>>>(part, patch_b, pos, t);

    for (int i = 0; i < DEPTH; ++i){
        const float* cw0  = cw[0]   + (size_t)i * CDIM * DCONV;
        const float* cw1  = cw[1]   + (size_t)i * CDIM * DCONV;
        const float* cb0  = cb[0]   + (size_t)i * CDIM;
        const float* cb1  = cb[1]   + (size_t)i * CDIM;
        const float* dtb0 = dtb[0]  + (size_t)i * H;
        const float* dtb1 = dtb[1]  + (size_t)i * H;
        const float* Al0  = Alog[0] + (size_t)i * H;
        const float* Al1  = Alog[1] + (size_t)i * H;
        const float* Dp0  = Dp[0]   + (size_t)i * H;
        const float* Dp1  = Dp[1]   + (size_t)i * H;
        const float* gn0  = gn[0]   + (size_t)i * DIN;
        const float* gn1  = gn[1]   + (size_t)i * DIN;
        const ushort_t* Wi0 = win_bf  + (size_t)(2 * i + 0) * 296960;
        const ushort_t* Wi1 = win_bf  + (size_t)(2 * i + 1) * 296960;
        const ushort_t* Wo0 = wout_bf + (size_t)(2 * i + 0) * 131072;
        const ushort_t* Wo1 = wout_bf + (size_t)(2 * i + 1) * 131072;

        gemm_in_k<<<dim3(19, 16, 2), 256, 0, stream>>>(
            t, norms_w + i * D, Wi0, Wi1, zx0, zx1);
        conv_silu_k<<<dim3(L, BATCH, 2), 256, 0, stream>>>(
            zx0, zx1, cw0, cw1, cb0, cb1, xy0, xy1, bcb0, bcb1);
        yscan2_k<<<dim3(H, BATCH, 2), 512, 0, stream>>>(
            zx0, zx1, bcb0, bcb1, dtb0, dtb1, Al0, Al1, Dp0, Dp1, xy0, xy1);
        gate_rmsnorm_k<<<dim3(BL, 2), 256, 0, stream>>>(
            xy0, xy1, zx0, zx1, gn0, gn1, ybf0, ybf1);
        gemm_out_k<<<dim3(4, 16, 8), 256, 0, stream>>>(ybf0, ybf1, Wo0, Wo1, part);
        out_red_k<<<BL, 256, 0, stream>>>(part, t);
    }

    finalmean_k<<<BATCH, 1024, 0, stream>>>(t, final_w, tm);
    head_k<<<dim3((BATCH * NCLS + 255) / 256, 4), 256, 0, stream>>>(tm, head_w, hpart);
    head_red_k<<<(BATCH * NCLS + 255) / 256, 256, 0, stream>>>(
        hpart, head_b, (float*)d_out);
}